// Round 1
// baseline (112.691 us; speedup 1.0000x reference)
//
#include <hip/hip_runtime.h>
#include <math.h>

namespace {
constexpr int B = 2;
constexpr int S = 2048;
constexpr int D = 2048;
constexpr float EPS = 1e-6f;
constexpr int THREADS = 512;   // 512 threads x float4 = 2048 = D

__global__ __launch_bounds__(THREADS) void gated_kernel(
    const float* __restrict__ x,
    const float* __restrict__ weight,   // (D, 4) row-major
    const float* __restrict__ alpha,    // (3,)
    const float* __restrict__ rms_w,    // (D,)
    float* __restrict__ out)
{
    const int bs  = blockIdx.x;           // 0 .. B*S-1
    const int b   = bs >> 11;             // / S   (S = 2048)
    const int s   = bs & (S - 1);         // % S
    const int tid = threadIdx.x;
    const int d   = tid << 2;             // this thread's 4 consecutive d's

    const float* xb = x + ((size_t)b * S) * D;

    // xa[j][c] = x[b, s-j, d+c]  (zero-padded for s-j < 0), j = 0..5
    float xa[6][4];
#pragma unroll
    for (int j = 0; j < 6; ++j) {
        const int ss = s - j;
        if (ss >= 0) {
            const float4 v = *reinterpret_cast<const float4*>(xb + (size_t)ss * D + d);
            xa[j][0] = v.x; xa[j][1] = v.y; xa[j][2] = v.z; xa[j][3] = v.w;
        } else {
            xa[j][0] = xa[j][1] = xa[j][2] = xa[j][3] = 0.f;
        }
    }

    // wv[c][k] = weight[(d+c), k] — 16 contiguous floats starting at weight + d*4
    float wv[4][4];
#pragma unroll
    for (int c = 0; c < 4; ++c) {
        const float4 t = *reinterpret_cast<const float4*>(weight + ((size_t)(d + c) << 2));
        wv[c][0] = t.x; wv[c][1] = t.y; wv[c][2] = t.z; wv[c][3] = t.w;
    }

    // 8 partial reductions: part[k] = dot(x[s], x[s-k]); part[4+k] = sum(pre_k^2)
    float part[8];
#pragma unroll
    for (int k = 0; k < 4; ++k) {
        float dk = 0.f, sk = 0.f;
#pragma unroll
        for (int c = 0; c < 4; ++c) {
            dk += xa[0][c] * xa[k][c];
            const float p = xa[k][c] * xa[k + 2][c] * wv[c][k];
            sk += p * p;
        }
        part[k]     = dk;
        part[4 + k] = sk;
    }

    // wave-64 butterfly-free shfl_down reduction
#pragma unroll
    for (int off = 32; off > 0; off >>= 1) {
#pragma unroll
        for (int i = 0; i < 8; ++i)
            part[i] += __shfl_down(part[i], off, 64);
    }

    __shared__ float sdata[8][8];   // [wave][value]
    __shared__ float red[8];
    __shared__ float cbc[4];
    const int wave = tid >> 6;
    if ((tid & 63) == 0) {
#pragma unroll
        for (int i = 0; i < 8; ++i) sdata[wave][i] = part[i];
    }
    __syncthreads();
    if (tid < 8) {
        float v = 0.f;
#pragma unroll
        for (int w = 0; w < 8; ++w) v += sdata[w][tid];
        red[tid] = v;
    }
    __syncthreads();
    if (tid < 4) {
        const float lam = (tid == 0) ? 1.f : tanhf(red[tid] * alpha[tid - 1]);
        const float inv = rsqrtf(red[4 + tid] * (1.f / (float)D) + EPS);
        cbc[tid] = lam * inv;
    }
    __syncthreads();

    const float ck[4] = {cbc[0], cbc[1], cbc[2], cbc[3]};

    const float4 rv = *reinterpret_cast<const float4*>(rms_w + d);
    const float rms[4] = {rv.x, rv.y, rv.z, rv.w};

    float oc[4];
#pragma unroll
    for (int c = 0; c < 4; ++c) {
        float acc = 0.f;
#pragma unroll
        for (int k = 0; k < 4; ++k) {
            acc += ck[k] * wv[c][k] * wv[c][k] * xa[k][c] * xa[k + 2][c];
        }
        oc[c] = xa[0][c] + rms[c] * acc;
    }
    const float4 ov = make_float4(oc[0], oc[1], oc[2], oc[3]);
    *reinterpret_cast<float4*>(out + (size_t)bs * D + d) = ov;
}
} // namespace

extern "C" void kernel_launch(void* const* d_in, const int* in_sizes, int n_in,
                              void* d_out, int out_size, void* d_ws, size_t ws_size,
                              hipStream_t stream) {
    const float* x      = (const float*)d_in[0];
    const float* weight = (const float*)d_in[1];
    const float* alpha  = (const float*)d_in[2];
    const float* rms_w  = (const float*)d_in[3];
    float* out          = (float*)d_out;

    gated_kernel<<<dim3(B * S), dim3(THREADS), 0, stream>>>(x, weight, alpha, rms_w, out);
}

// Round 2
// 105.573 us; speedup vs baseline: 1.0674x; 1.0674x over previous
//
#include <hip/hip_runtime.h>
#include <math.h>

namespace {
constexpr int B = 2;
constexpr int S = 2048;
constexpr int D = 2048;
constexpr int T = 8;              // rows per block
constexpr float EPS = 1e-6f;
constexpr int THREADS = 512;      // 512 threads x float4 = 2048 = D
constexpr int NROWS = T + 5;      // 13 rows resident per block

__global__ __launch_bounds__(THREADS) void gated_kernel(
    const float* __restrict__ x,
    const float* __restrict__ weight,   // (D, 4) row-major
    const float* __restrict__ alpha,    // (3,)
    const float* __restrict__ rms_w,    // (D,)
    float* __restrict__ out)
{
    const int blk = blockIdx.x;          // 0 .. B*(S/T)-1
    const int b   = blk >> 8;            // / (S/T), S/T = 256
    const int s0  = (blk & 255) << 3;    // * T
    const int tid = threadIdx.x;
    const int d   = tid << 2;
    const int wave = tid >> 6;
    const int lane = tid & 63;

    const float* xb = x + ((size_t)b * S) * D;

    // xr[j][c] = x[b, s0-5+j, d+c], zero-padded for negative rows.
    // Row s0+t is xr[t+5]; x[s0+t-k] = xr[t+5-k]; x[s0+t-k-2] = xr[t+3-k].
    float xr[NROWS][4];
#pragma unroll
    for (int j = 0; j < NROWS; ++j) {
        const int ss = s0 - 5 + j;       // block-uniform → no divergence
        if (ss >= 0) {
            const float4 v = *reinterpret_cast<const float4*>(xb + (size_t)ss * D + d);
            xr[j][0] = v.x; xr[j][1] = v.y; xr[j][2] = v.z; xr[j][3] = v.w;
        } else {
            xr[j][0] = xr[j][1] = xr[j][2] = xr[j][3] = 0.f;
        }
    }

    // Only w^2 is ever needed (sumsq uses (g*w)^2, epilogue uses w^2).
    float wsq[4][4];
#pragma unroll
    for (int c = 0; c < 4; ++c) {
        const float4 t4 = *reinterpret_cast<const float4*>(weight + ((size_t)(d + c) << 2));
        wsq[c][0] = t4.x * t4.x; wsq[c][1] = t4.y * t4.y;
        wsq[c][2] = t4.z * t4.z; wsq[c][3] = t4.w * t4.w;
    }

    // Per-(row, wave) partials: vals[0..2] = dot k=1..3, vals[3..6] = sumsq k=0..3
    __shared__ float pl[T][8][7];

#pragma unroll
    for (int t = 0; t < T; ++t) {
        float pv[7];
#pragma unroll
        for (int k = 1; k < 4; ++k) {
            float dk = 0.f;
#pragma unroll
            for (int c = 0; c < 4; ++c) dk += xr[t + 5][c] * xr[t + 5 - k][c];
            pv[k - 1] = dk;
        }
#pragma unroll
        for (int k = 0; k < 4; ++k) {
            float sk = 0.f;
#pragma unroll
            for (int c = 0; c < 4; ++c) {
                const float g = xr[t + 5 - k][c] * xr[t + 3 - k][c];
                sk += g * g * wsq[c][k];
            }
            pv[3 + k] = sk;
        }
#pragma unroll
        for (int off = 32; off > 0; off >>= 1) {
#pragma unroll
            for (int i = 0; i < 7; ++i) pv[i] += __shfl_down(pv[i], off, 64);
        }
        if (lane == 0) {
#pragma unroll
            for (int i = 0; i < 7; ++i) pl[t][wave][i] = pv[i];
        }
    }
    __syncthreads();

    __shared__ float cbc[T][4];
    if (tid < T * 4) {
        const int t = tid >> 2, k = tid & 3;
        float ss = 0.f;
#pragma unroll
        for (int w = 0; w < 8; ++w) ss += pl[t][w][3 + k];
        float lam = 1.f;
        if (k > 0) {
            float dd = 0.f;
#pragma unroll
            for (int w = 0; w < 8; ++w) dd += pl[t][w][k - 1];
            lam = tanhf(dd * alpha[k - 1]);
        }
        cbc[t][k] = lam * rsqrtf(ss * (1.f / (float)D) + EPS);
    }
    __syncthreads();

    const float4 rv = *reinterpret_cast<const float4*>(rms_w + d);
    const float rms[4] = {rv.x, rv.y, rv.z, rv.w};

    float* ob = out + ((size_t)b * S + (size_t)s0) * D + d;
#pragma unroll
    for (int t = 0; t < T; ++t) {
        const float c0 = cbc[t][0], c1 = cbc[t][1], c2 = cbc[t][2], c3 = cbc[t][3];
        float oc[4];
#pragma unroll
        for (int c = 0; c < 4; ++c) {
            const float acc = c0 * wsq[c][0] * (xr[t + 5][c] * xr[t + 3][c])
                            + c1 * wsq[c][1] * (xr[t + 4][c] * xr[t + 2][c])
                            + c2 * wsq[c][2] * (xr[t + 3][c] * xr[t + 1][c])
                            + c3 * wsq[c][3] * (xr[t + 2][c] * xr[t + 0][c]);
            oc[c] = xr[t + 5][c] + rms[c] * acc;
        }
        const float4 ov = make_float4(oc[0], oc[1], oc[2], oc[3]);
        *reinterpret_cast<float4*>(ob + (size_t)t * D) = ov;
    }
}
} // namespace

extern "C" void kernel_launch(void* const* d_in, const int* in_sizes, int n_in,
                              void* d_out, int out_size, void* d_ws, size_t ws_size,
                              hipStream_t stream) {
    const float* x      = (const float*)d_in[0];
    const float* weight = (const float*)d_in[1];
    const float* alpha  = (const float*)d_in[2];
    const float* rms_w  = (const float*)d_in[3];
    float* out          = (float*)d_out;

    gated_kernel<<<dim3(B * (S / T)), dim3(THREADS), 0, stream>>>(x, weight, alpha, rms_w, out);
}

// Round 3
// 95.121 us; speedup vs baseline: 1.1847x; 1.1099x over previous
//
#include <hip/hip_runtime.h>
#include <math.h>

namespace {
constexpr int B = 2;
constexpr int S = 2048;
constexpr int D = 2048;
constexpr int T = 16;             // rows per block
constexpr float EPS = 1e-6f;
constexpr int THREADS = 512;      // 512 threads x float4 = 2048 = D
constexpr int NROWS = T + 5;      // 21 rows resident per block

__global__ __launch_bounds__(THREADS, 2) void gated_kernel(
    const float* __restrict__ x,
    const float* __restrict__ weight,   // (D, 4) row-major
    const float* __restrict__ alpha,    // (3,)
    const float* __restrict__ rms_w,    // (D,)
    float* __restrict__ out)
{
    const int blk = blockIdx.x;          // 0 .. B*(S/T)-1, S/T = 128
    const int b   = blk >> 7;
    const int s0  = (blk & 127) << 4;    // * T
    const int tid = threadIdx.x;
    const int d   = tid << 2;
    const int wave = tid >> 6;
    const int lane = tid & 63;

    const float* xb = x + ((size_t)b * S) * D;

    // xr[j][c] = x[b, s0-5+j, d+c], zero-padded for negative rows.
    // Row s0+t is xr[t+5]; x[s0+t-k] = xr[t+5-k]; x[s0+t-k-2] = xr[t+3-k].
    float xr[NROWS][4];
#pragma unroll
    for (int j = 0; j < NROWS; ++j) {
        const int ss = s0 - 5 + j;       // block-uniform → no divergence
        if (ss >= 0) {
            const float4 v = *reinterpret_cast<const float4*>(xb + (size_t)ss * D + d);
            xr[j][0] = v.x; xr[j][1] = v.y; xr[j][2] = v.z; xr[j][3] = v.w;
        } else {
            xr[j][0] = xr[j][1] = xr[j][2] = xr[j][3] = 0.f;
        }
    }

    // Only w^2 is ever needed.
    float wsq[4][4];
#pragma unroll
    for (int c = 0; c < 4; ++c) {
        const float4 t4 = *reinterpret_cast<const float4*>(weight + ((size_t)(d + c) << 2));
        wsq[c][0] = t4.x * t4.x; wsq[c][1] = t4.y * t4.y;
        wsq[c][2] = t4.z * t4.z; wsq[c][3] = t4.w * t4.w;
    }

    // pl[row][value][wave]: value 0..2 = dot k=1..3, 3..6 = sumsq k=0..3
    __shared__ float pl[T][8][8];
    __shared__ float cbc[T][4];

#pragma unroll
    for (int t = 0; t < T; ++t) {
        float v[8];
#pragma unroll
        for (int k = 1; k < 4; ++k) {
            float dk = 0.f;
#pragma unroll
            for (int c = 0; c < 4; ++c) dk += xr[t + 5][c] * xr[t + 5 - k][c];
            v[k - 1] = dk;
        }
#pragma unroll
        for (int k = 0; k < 4; ++k) {
            float sk = 0.f;
#pragma unroll
            for (int c = 0; c < 4; ++c) {
                const float g = xr[t + 5 - k][c] * xr[t + 3 - k][c];
                sk += g * g * wsq[c][k];
            }
            v[3 + k] = sk;
        }
        v[7] = 0.f;

        // Reduce-scatter butterfly: 8 values over 64 lanes in 10 shfl.
        const bool b0 = (lane & 1), b1 = (lane & 2), b2 = (lane & 4);
        float w4[4];
#pragma unroll
        for (int i = 0; i < 4; ++i) {
            const float keep  = b0 ? v[i + 4] : v[i];
            const float other = b0 ? v[i]     : v[i + 4];
            w4[i] = keep + __shfl_xor(other, 1, 64);
        }
        float u2[2];
#pragma unroll
        for (int i = 0; i < 2; ++i) {
            const float keep  = b1 ? w4[i + 2] : w4[i];
            const float other = b1 ? w4[i]     : w4[i + 2];
            u2[i] = keep + __shfl_xor(other, 2, 64);
        }
        {
            const float keep  = b2 ? u2[1] : u2[0];
            const float other = b2 ? u2[0] : u2[1];
            float r = keep + __shfl_xor(other, 4, 64);
            r += __shfl_down(r, 8, 64);
            r += __shfl_down(r, 16, 64);
            r += __shfl_down(r, 32, 64);
            if (lane < 8) {
                // lane holds total of value idx = bitrev3(lane)
                const int vidx = ((lane & 1) << 2) | (lane & 2) | ((lane >> 2) & 1);
                pl[t][vidx][wave] = r;
            }
        }
    }
    __syncthreads();

    if (tid < T * 4) {
        const int t = tid >> 2, k = tid & 3;
        float ss = 0.f;
#pragma unroll
        for (int w = 0; w < 8; ++w) ss += pl[t][3 + k][w];
        float lam = 1.f;
        if (k > 0) {
            float dd = 0.f;
#pragma unroll
            for (int w = 0; w < 8; ++w) dd += pl[t][k - 1][w];
            lam = tanhf(dd * alpha[k - 1]);
        }
        cbc[t][k] = lam * rsqrtf(ss * (1.f / (float)D) + EPS);
    }
    __syncthreads();

    const float4 rv = *reinterpret_cast<const float4*>(rms_w + d);
    const float rms[4] = {rv.x, rv.y, rv.z, rv.w};

    float* ob = out + ((size_t)b * S + (size_t)s0) * D + d;
#pragma unroll
    for (int t = 0; t < T; ++t) {
        const float c0 = cbc[t][0], c1 = cbc[t][1], c2 = cbc[t][2], c3 = cbc[t][3];
        float oc[4];
#pragma unroll
        for (int c = 0; c < 4; ++c) {
            const float acc = c0 * wsq[c][0] * (xr[t + 5][c] * xr[t + 3][c])
                            + c1 * wsq[c][1] * (xr[t + 4][c] * xr[t + 2][c])
                            + c2 * wsq[c][2] * (xr[t + 3][c] * xr[t + 1][c])
                            + c3 * wsq[c][3] * (xr[t + 2][c] * xr[t + 0][c]);
            oc[c] = xr[t + 5][c] + rms[c] * acc;
        }
        const float4 ov = make_float4(oc[0], oc[1], oc[2], oc[3]);
        *reinterpret_cast<float4*>(ob + (size_t)t * D) = ov;
    }
}
} // namespace

extern "C" void kernel_launch(void* const* d_in, const int* in_sizes, int n_in,
                              void* d_out, int out_size, void* d_ws, size_t ws_size,
                              hipStream_t stream) {
    const float* x      = (const float*)d_in[0];
    const float* weight = (const float*)d_in[1];
    const float* alpha  = (const float*)d_in[2];
    const float* rms_w  = (const float*)d_in[3];
    float* out          = (float*)d_out;

    gated_kernel<<<dim3(B * (S / T)), dim3(THREADS), 0, stream>>>(x, weight, alpha, rms_w, out);
}

// Round 5
// 92.904 us; speedup vs baseline: 1.2130x; 1.0239x over previous
//
#include <hip/hip_runtime.h>
#include <math.h>

namespace {
constexpr int B = 2;
constexpr int S = 2048;
constexpr int D = 2048;
constexpr int T = 16;             // rows per block
constexpr int G = 4;              // rows per pipeline group
constexpr float EPS = 1e-6f;
constexpr int THREADS = 512;      // 512 threads x float4 = 2048 = D
constexpr int NROWS = T + 5;      // 21 rows resident per block

typedef float floatx4 __attribute__((ext_vector_type(4)));  // native vec for nontemporal builtin

__global__ __launch_bounds__(THREADS, 2) void gated_kernel(
    const float* __restrict__ x,
    const float* __restrict__ weight,   // (D, 4) row-major
    const float* __restrict__ alpha,    // (3,)
    const float* __restrict__ rms_w,    // (D,)
    float* __restrict__ out)
{
    const int blk = blockIdx.x;          // 0 .. B*(S/T)-1, S/T = 128
    const int b   = blk >> 7;
    const int s0  = (blk & 127) << 4;    // * T
    const int tid = threadIdx.x;
    const int d   = tid << 2;
    const int wave = tid >> 6;
    const int lane = tid & 63;

    const float* xb = x + ((size_t)b * S) * D;

    // xr[j][c] = x[b, s0-5+j, d+c], zero-padded for negative rows.
    // Row s0+t is xr[t+5]; x[s0+t-k] = xr[t+5-k]; x[s0+t-k-2] = xr[t+3-k].
    float xr[NROWS][4];
#pragma unroll
    for (int j = 0; j < NROWS; ++j) {
        const int ss = s0 - 5 + j;       // block-uniform → no divergence
        if (ss >= 0) {
            const float4 v = *reinterpret_cast<const float4*>(xb + (size_t)ss * D + d);
            xr[j][0] = v.x; xr[j][1] = v.y; xr[j][2] = v.z; xr[j][3] = v.w;
        } else {
            xr[j][0] = xr[j][1] = xr[j][2] = xr[j][3] = 0.f;
        }
    }

    // Only w^2 is ever needed.
    float wsq[4][4];
#pragma unroll
    for (int c = 0; c < 4; ++c) {
        const float4 t4 = *reinterpret_cast<const float4*>(weight + ((size_t)(d + c) << 2));
        wsq[c][0] = t4.x * t4.x; wsq[c][1] = t4.y * t4.y;
        wsq[c][2] = t4.z * t4.z; wsq[c][3] = t4.w * t4.w;
    }

    const float4 rv = *reinterpret_cast<const float4*>(rms_w + d);
    const float rms[4] = {rv.x, rv.y, rv.z, rv.w};

    // pl[row][value][wave]: value 0..2 = dot k=1..3, 3..6 = sumsq k=0..3
    __shared__ float pl[T][8][8];
    __shared__ float cbc[T][4];

    float* ob = out + ((size_t)b * S + (size_t)s0) * D + d;

#pragma unroll
    for (int g = 0; g < T / G; ++g) {
        // ---- reduce G rows ----
#pragma unroll
        for (int tg = 0; tg < G; ++tg) {
            const int t = g * G + tg;
            float v[8];
#pragma unroll
            for (int k = 1; k < 4; ++k) {
                float dk = 0.f;
#pragma unroll
                for (int c = 0; c < 4; ++c) dk += xr[t + 5][c] * xr[t + 5 - k][c];
                v[k - 1] = dk;
            }
#pragma unroll
            for (int k = 0; k < 4; ++k) {
                float sk = 0.f;
#pragma unroll
                for (int c = 0; c < 4; ++c) {
                    const float gg = xr[t + 5 - k][c] * xr[t + 3 - k][c];
                    sk += gg * gg * wsq[c][k];
                }
                v[3 + k] = sk;
            }
            v[7] = 0.f;

            // Reduce-scatter butterfly: 8 values over 64 lanes in 10 shfl.
            const bool b0 = (lane & 1), b1 = (lane & 2), b2 = (lane & 4);
            float w4[4];
#pragma unroll
            for (int i = 0; i < 4; ++i) {
                const float keep  = b0 ? v[i + 4] : v[i];
                const float other = b0 ? v[i]     : v[i + 4];
                w4[i] = keep + __shfl_xor(other, 1, 64);
            }
            float u2[2];
#pragma unroll
            for (int i = 0; i < 2; ++i) {
                const float keep  = b1 ? w4[i + 2] : w4[i];
                const float other = b1 ? w4[i]     : w4[i + 2];
                u2[i] = keep + __shfl_xor(other, 2, 64);
            }
            {
                const float keep  = b2 ? u2[1] : u2[0];
                const float other = b2 ? u2[0] : u2[1];
                float r = keep + __shfl_xor(other, 4, 64);
                r += __shfl_down(r, 8, 64);
                r += __shfl_down(r, 16, 64);
                r += __shfl_down(r, 32, 64);
                if (lane < 8) {
                    const int vidx = ((lane & 1) << 2) | (lane & 2) | ((lane >> 2) & 1);
                    pl[t][vidx][wave] = r;
                }
            }
        }
        __syncthreads();

        // ---- cbc for this group's G rows (G*4 = 16 threads) ----
        if (tid < G * 4) {
            const int t = g * G + (tid >> 2), k = tid & 3;
            float ss = 0.f;
#pragma unroll
            for (int w = 0; w < 8; ++w) ss += pl[t][3 + k][w];
            float lam = 1.f;
            if (k > 0) {
                float dd = 0.f;
#pragma unroll
                for (int w = 0; w < 8; ++w) dd += pl[t][k - 1][w];
                lam = tanhf(dd * alpha[k - 1]);
            }
            cbc[t][k] = lam * rsqrtf(ss * (1.f / (float)D) + EPS);
        }
        __syncthreads();

        // ---- epilogue + NT store for this group's G rows ----
#pragma unroll
        for (int tg = 0; tg < G; ++tg) {
            const int t = g * G + tg;
            const float c0 = cbc[t][0], c1 = cbc[t][1], c2 = cbc[t][2], c3 = cbc[t][3];
            floatx4 ov;
#pragma unroll
            for (int c = 0; c < 4; ++c) {
                const float acc = c0 * wsq[c][0] * (xr[t + 5][c] * xr[t + 3][c])
                                + c1 * wsq[c][1] * (xr[t + 4][c] * xr[t + 2][c])
                                + c2 * wsq[c][2] * (xr[t + 3][c] * xr[t + 1][c])
                                + c3 * wsq[c][3] * (xr[t + 2][c] * xr[t + 0][c]);
                ov[c] = xr[t + 5][c] + rms[c] * acc;
            }
            __builtin_nontemporal_store(ov, reinterpret_cast<floatx4*>(ob + (size_t)t * D));
        }
    }
}
} // namespace

extern "C" void kernel_launch(void* const* d_in, const int* in_sizes, int n_in,
                              void* d_out, int out_size, void* d_ws, size_t ws_size,
                              hipStream_t stream) {
    const float* x      = (const float*)d_in[0];
    const float* weight = (const float*)d_in[1];
    const float* alpha  = (const float*)d_in[2];
    const float* rms_w  = (const float*)d_in[3];
    float* out          = (float*)d_out;

    gated_kernel<<<dim3(B * (S / T)), dim3(THREADS), 0, stream>>>(x, weight, alpha, rms_w, out);
}